// Round 15
// baseline (73.082 us; speedup 1.0000x reference)
//
#include <hip/hip_runtime.h>

// TimeTempTransformerModule: MLP(1->16->32) -> biGRU(H=32, SEQ=32) -> meanpool -> dec(64->128)
// B = 32768 rows, fp32 in/out.
//
// v14 = v12 (PASSING numerics: 2-term gh = rne(W)*(h_hi+h_lo), 18 MFMA/step,
// swapped-operand recurrence, 4 waves/256-thr block, r/z -log2e fold) plus:
//  1) n-gate 2*log2e fold (from v13; error-free): tanh arg feeds exp2 directly,
//     kills 8 muls/step. v13's FAILURE was the 1-term gh (h at bf16-rne 2^-9,
//     absmax 8.8e-3) -- NOT the folds. 2-term restored here.
//  2) x software-prefetch by one 8-step block: the 2xfloat4 x-loads were issued
//     right before use in an unroll-1 loop -> ~500cy exposed L2 latency every
//     8 steps. Now issued a block early (~1300cy of compute cover).
//  3) RNE packs via v_cvt_pk_bf16_f32 for the lo-residual and h1 frags (same
//     op count as trunc perm packs, strictly more accurate).
// (Round 14 bench was lost to an unresponsive container; identical resubmission.)

#define SEQB 32
#define NH   16
#define DH   32

typedef __attribute__((ext_vector_type(4))) float f32x4;
typedef __attribute__((ext_vector_type(8))) short s16x8;
typedef __attribute__((ext_vector_type(4))) unsigned int u32x4;

#define MFMA_B16(a, b, c) __builtin_amdgcn_mfma_f32_16x16x32_bf16((a), (b), (c), 0, 0, 0)

#define NLOG2E  -1.4426950408889634f
#define TWOLOG2E 2.8853900817779268f

// ws layout (bytes)
#define OFF_AHI  0u        // [dir][t<6][lane<64] 16B  gh weights (rne, gate-scaled)
#define OFF_AGX  24576u    // [dir][t<6][lane] 16B     gx weights (rne, gate-scaled) + bias slots
#define OFF_ADEC 36864u    // [kc<2][t<8][lane] 16B    decoder weights (rne)
#define OFF_WC   53248u    // [dir][96][16] f32 temp
#define OFF_BC   65536u    // [dir][96] f32 temp

__device__ __forceinline__ unsigned short bf16_rne(float x) {
    unsigned u = __float_as_uint(x);
    return (unsigned short)((u + 0x7fffu + ((u >> 16) & 1u)) >> 16);
}
// (a & 0xffff0000) | (b >> 16)  -- trunc pack (hi parts + decoder)
__device__ __forceinline__ unsigned pack_hi(unsigned a, unsigned b) {
    return __builtin_amdgcn_perm(a, b, 0x07060302u);
}
// RNE pack of two floats into one u32: lo16 = bf16(a), hi16 = bf16(b). 1 op.
__device__ __forceinline__ unsigned cvt_pk_bf16(float a, float b) {
    unsigned r;
    asm("v_cvt_pk_bf16_f32 %0, %1, %2" : "=v"(r) : "v"(a), "v"(b));
    return r;
}
__device__ __forceinline__ int kperm(int q, int e) {  // pi(q,e)
    return (e < 4) ? (4 * q + e) : (4 * q + 12 + e);
}

__global__ __launch_bounds__(1024) void gru_precompute_kernel(
    const float* __restrict__ w_ih_f, const float* __restrict__ b_ih_f,
    const float* __restrict__ w_ih_b, const float* __restrict__ b_ih_b,
    const float* __restrict__ w2, const float* __restrict__ b2,
    const float* __restrict__ whh_f, const float* __restrict__ whh_b,
    const float* __restrict__ bhh_f, const float* __restrict__ bhh_b,
    const float* __restrict__ w_dec,
    unsigned char* __restrict__ ws)
{
    const int t = threadIdx.x;
    float* WC = (float*)(ws + OFF_WC);
    float* BC = (float*)(ws + OFF_BC);

    if (t < 192) {  // Wc = w_ih@w2 [96x16], bc = w_ih@b2 + b_ih
        const int dir = t / 96, g = t % 96;
        const float* wih = dir ? w_ih_b : w_ih_f;
        const float* bih = dir ? b_ih_b : b_ih_f;
        float acc[NH];
#pragma unroll
        for (int m = 0; m < NH; ++m) acc[m] = 0.0f;
        float ab = bih[g];
        for (int d = 0; d < DH; ++d) {
            float wv = wih[g * DH + d];
            ab = fmaf(wv, b2[d], ab);
#pragma unroll
            for (int m = 0; m < NH; ++m) acc[m] = fmaf(wv, w2[d * NH + m], acc[m]);
        }
#pragma unroll
        for (int m = 0; m < NH; ++m) WC[(dir * 96 + g) * NH + m] = acc[m];
        BC[dir * 96 + g] = ab;
    }
    __syncthreads();

    if (t < 768) {  // gh A-frags (rne, k-permuted, gate-scaled) + gx A-frags
        const int dir = t / 384, r = t % 384, tt = r / 64, l = r % 64;
        const int gate = tt * 16 + (l & 15);
        const int q = l >> 4;
        const float* whh = dir ? whh_b : whh_f;
        const float* bhh = dir ? bhh_b : bhh_f;
        // r/z gates (0..63): fold -log2e -> sigma(x) = rcp(1+exp2(a)).
        // n gates (64..95): fold 2*log2e -> tanh arg feeds exp2 directly.
        const float sc = (gate < 64) ? NLOG2E : TWOLOG2E;
        unsigned short h8[8], g8[8];
#pragma unroll
        for (int e = 0; e < 8; ++e) {
            const int u = kperm(q, e);
            h8[e] = bf16_rne(whh[gate * DH + u] * sc);
            float gxv = (e < 4) ? WC[(dir * 96 + gate) * NH + 4 * q + e] : 0.0f;
            g8[e] = bf16_rne(gxv * sc);
        }
        // bias slots: (q=0,e=4) hi, (q=1,e=4) lo; pairs with constant 1.0 in B.
        // r/z: (bc + bhh) * -log2e ; n: bc * 2log2e (bhh_n applied in C-init).
        const float bias = (BC[dir * 96 + gate] + ((gate < 64) ? bhh[gate] : 0.0f)) * sc;
        const unsigned bb = __float_as_uint(bias);
        if (q == 0) g8[4] = (unsigned short)(bb >> 16);
        if (q == 1) g8[4] = bf16_rne(bias - __uint_as_float(bb & 0xffff0000u));

        unsigned short* dh = (unsigned short*)(ws + OFF_AHI + dir * 6144u + tt * 1024u + l * 16u);
        unsigned short* dg = (unsigned short*)(ws + OFF_AGX + dir * 6144u + tt * 1024u + l * 16u);
#pragma unroll
        for (int e = 0; e < 8; ++e) { dh[e] = h8[e]; dg[e] = g8[e]; }
    }
    {  // decoder A-frags: A[out][k] k-permuted, k = pi(q,e) + 32*kc
        const int kc = t / 512, r = t % 512, tt = r / 64, l = r % 64;
        const int outn = tt * 16 + (l & 15);
        const int q = l >> 4;
        unsigned short* dd = (unsigned short*)(ws + OFF_ADEC + kc * 8192u + tt * 1024u + l * 16u);
#pragma unroll
        for (int e = 0; e < 8; ++e)
            dd[e] = bf16_rne(w_dec[outn * 64 + kperm(q, e) + 32 * kc]);
    }
}

__global__ __launch_bounds__(256, 2) void gru_mfma_kernel(
    const float* __restrict__ x,
    const float* __restrict__ w1, const float* __restrict__ b1,
    const float* __restrict__ bhh_f, const float* __restrict__ bhh_b,
    const unsigned char* __restrict__ ws,
    const float* __restrict__ b_dec,
    float* __restrict__ out)
{
    const int tid = threadIdx.x;
    const int wv  = tid >> 6;   // wave in block (0..3), fully independent
    const int l   = tid & 63;
    const int n = l & 15;       // batch row (D col / B col)
    const int q = l >> 4;       // k-quad / D row-quad
    const int rowbase = blockIdx.x * 64 + wv * 16;
    const float* xr = x + (size_t)(rowbase + n) * SEQB;

    const float4 w1q = *(const float4*)(w1 + 4 * q);  // h1 units 4q..4q+3
    const float4 b1q = *(const float4*)(b1 + 4 * q);

    float pFL[4], pFH[4], pBL[4], pBH[4];

#pragma unroll 1
    for (int dir = 0; dir < 2; ++dir) {
        const float* bhh = dir ? bhh_b : bhh_f;
        const unsigned char* pAhi = ws + OFF_AHI + dir * 6144u + l * 16u;
        const unsigned char* pAgx = ws + OFF_AGX + dir * 6144u + l * 16u;
        s16x8 Ahi[6], Agx[6];
#pragma unroll
        for (int tt = 0; tt < 6; ++tt) {
            Ahi[tt] = *(const s16x8*)(pAhi + tt * 1024);
            Agx[tt] = *(const s16x8*)(pAgx + tt * 1024);
        }
#pragma unroll
        for (int tt = 0; tt < 6; ++tt)
            asm volatile("" : "+v"(Ahi[tt]), "+v"(Agx[tt]));
        // n-gate gh bias (C-init of the gh chain), pre-scaled by 2*log2e
        const float4 bn0f = *(const float4*)(bhh + 64 + 4 * q);
        const float4 bn1f = *(const float4*)(bhh + 80 + 4 * q);
        const f32x4 bhn0 = {bn0f.x * TWOLOG2E, bn0f.y * TWOLOG2E,
                            bn0f.z * TWOLOG2E, bn0f.w * TWOLOG2E};
        const f32x4 bhn1 = {bn1f.x * TWOLOG2E, bn1f.y * TWOLOG2E,
                            bn1f.z * TWOLOG2E, bn1f.w * TWOLOG2E};

        float hL[4] = {0, 0, 0, 0}, hH[4] = {0, 0, 0, 0};
        float pL[4] = {0, 0, 0, 0}, pH[4] = {0, 0, 0, 0};

        // x software-prefetch: current block in (xa,xb), next block loads
        // issued at the top of each iteration (hidden under 8 steps of compute).
        const int bb0 = dir ? 3 : 0;
        float4 xa = *(const float4*)(xr + bb0 * 8);
        float4 xb = *(const float4*)(xr + bb0 * 8 + 4);

#pragma unroll 1
        for (int blk = 0; blk < 4; ++blk) {
            float4 na = xa, nb = xb;
            if (blk < 3) {
                const int bbn = dir ? 2 - blk : blk + 1;
                na = *(const float4*)(xr + bbn * 8);
                nb = *(const float4*)(xr + bbn * 8 + 4);
            }
            const float raw[8] = {xa.x, xa.y, xa.z, xa.w, xb.x, xb.y, xb.z, xb.w};
            float xs[8];
#pragma unroll
            for (int i = 0; i < 8; ++i) xs[i] = dir ? raw[7 - i] : raw[i];

#pragma unroll
            for (int i = 0; i < 8; ++i) {
                // ---- B_h1 frag: h1[row n][4q+e] e<4 (in-lane, RNE), e4=1.0, e5..7=0
                float t0 = fmaf(xs[i], w1q.x, b1q.x); t0 = fmaxf(t0, 0.01f * t0);
                float t1 = fmaf(xs[i], w1q.y, b1q.y); t1 = fmaxf(t1, 0.01f * t1);
                float t2 = fmaf(xs[i], w1q.z, b1q.z); t2 = fmaxf(t2, 0.01f * t2);
                float t3 = fmaf(xs[i], w1q.w, b1q.w); t3 = fmaxf(t3, 0.01f * t3);
                u32x4 ub1;
                ub1.x = cvt_pk_bf16(t0, t1);
                ub1.y = cvt_pk_bf16(t2, t3);
                ub1.z = 0x00003F80u;  // e4 = 1.0 (bias partner), e5 = 0
                ub1.w = 0u;           // e6, e7 = 0
                const s16x8 Bh1 = __builtin_bit_cast(s16x8, ub1);

                // ---- B_h frags: trunc-hi (exact residual base) + RNE lo
                unsigned uL0 = __float_as_uint(hL[0]), uL1 = __float_as_uint(hL[1]);
                unsigned uL2 = __float_as_uint(hL[2]), uL3 = __float_as_uint(hL[3]);
                unsigned uH0 = __float_as_uint(hH[0]), uH1 = __float_as_uint(hH[1]);
                unsigned uH2 = __float_as_uint(hH[2]), uH3 = __float_as_uint(hH[3]);
                u32x4 phh;
                phh.x = pack_hi(uL1, uL0); phh.y = pack_hi(uL3, uL2);
                phh.z = pack_hi(uH1, uH0); phh.w = pack_hi(uH3, uH2);
                float lL0 = hL[0] - __uint_as_float(uL0 & 0xffff0000u);
                float lL1 = hL[1] - __uint_as_float(uL1 & 0xffff0000u);
                float lL2 = hL[2] - __uint_as_float(uL2 & 0xffff0000u);
                float lL3 = hL[3] - __uint_as_float(uL3 & 0xffff0000u);
                float lH0 = hH[0] - __uint_as_float(uH0 & 0xffff0000u);
                float lH1 = hH[1] - __uint_as_float(uH1 & 0xffff0000u);
                float lH2 = hH[2] - __uint_as_float(uH2 & 0xffff0000u);
                float lH3 = hH[3] - __uint_as_float(uH3 & 0xffff0000u);
                u32x4 phl;
                phl.x = cvt_pk_bf16(lL0, lL1);
                phl.y = cvt_pk_bf16(lL2, lL3);
                phl.z = cvt_pk_bf16(lH0, lH1);
                phl.w = cvt_pk_bf16(lH2, lH3);
                const s16x8 Bhhi = __builtin_bit_cast(s16x8, phh);
                const s16x8 Bhlo = __builtin_bit_cast(s16x8, phl);

                const f32x4 z4 = {0.0f, 0.0f, 0.0f, 0.0f};
                // r tiles: gx+bias then 2-term gh (rne W x (h_lo, h_hi)), one chain
                f32x4 a0 = MFMA_B16(Agx[0], Bh1, z4);
                a0 = MFMA_B16(Ahi[0], Bhlo, a0); a0 = MFMA_B16(Ahi[0], Bhhi, a0);
                f32x4 a1 = MFMA_B16(Agx[1], Bh1, z4);
                a1 = MFMA_B16(Ahi[1], Bhlo, a1); a1 = MFMA_B16(Ahi[1], Bhhi, a1);
                // z tiles
                f32x4 a2 = MFMA_B16(Agx[2], Bh1, z4);
                a2 = MFMA_B16(Ahi[2], Bhlo, a2); a2 = MFMA_B16(Ahi[2], Bhhi, a2);
                f32x4 a3 = MFMA_B16(Agx[3], Bh1, z4);
                a3 = MFMA_B16(Ahi[3], Bhlo, a3); a3 = MFMA_B16(Ahi[3], Bhhi, a3);
                // n tiles: gx (with bcn in bias slot) and gh (C-init = bhn) kept separate
                f32x4 x4a = MFMA_B16(Agx[4], Bh1, z4);
                f32x4 x5a = MFMA_B16(Agx[5], Bh1, z4);
                f32x4 g4 = MFMA_B16(Ahi[4], Bhlo, bhn0);
                g4 = MFMA_B16(Ahi[4], Bhhi, g4);
                f32x4 g5 = MFMA_B16(Ahi[5], Bhlo, bhn1);
                g5 = MFMA_B16(Ahi[5], Bhhi, g5);

                // ---- activations + state update (fp32; all scales pre-folded)
#pragma unroll
                for (int rg = 0; rg < 4; ++rg) {
                    float rL = __builtin_amdgcn_rcpf(1.0f + __builtin_amdgcn_exp2f(a0[rg]));
                    float zL = __builtin_amdgcn_rcpf(1.0f + __builtin_amdgcn_exp2f(a2[rg]));
                    float tL = fmaf(rL, g4[rg], x4a[rg]);
                    float nL = fmaf(-2.0f, __builtin_amdgcn_rcpf(1.0f + __builtin_amdgcn_exp2f(tL)), 1.0f);
                    hL[rg] = fmaf(zL, hL[rg] - nL, nL);
                    pL[rg] += hL[rg];

                    float rH = __builtin_amdgcn_rcpf(1.0f + __builtin_amdgcn_exp2f(a1[rg]));
                    float zH = __builtin_amdgcn_rcpf(1.0f + __builtin_amdgcn_exp2f(a3[rg]));
                    float tH = fmaf(rH, g5[rg], x5a[rg]);
                    float nH = fmaf(-2.0f, __builtin_amdgcn_rcpf(1.0f + __builtin_amdgcn_exp2f(tH)), 1.0f);
                    hH[rg] = fmaf(zH, hH[rg] - nH, nH);
                    pH[rg] += hH[rg];
                }
            }
            xa = na; xb = nb;
        }
        if (dir == 0) {
#pragma unroll
            for (int rg = 0; rg < 4; ++rg) { pFL[rg] = pL[rg]; pFH[rg] = pH[rg]; }
        } else {
#pragma unroll
            for (int rg = 0; rg < 4; ++rg) { pBL[rg] = pL[rg]; pBH[rg] = pH[rg]; }
        }
    }

    // ---- decoder: out[16x128] = pooled[16x64] @ w_dec^T + b_dec (swapped MFMA)
    {
#pragma unroll
        for (int rg = 0; rg < 4; ++rg) {
            pFL[rg] *= 0.03125f; pFH[rg] *= 0.03125f;
            pBL[rg] *= 0.03125f; pBH[rg] *= 0.03125f;
        }
        u32x4 pfh, pfl, pbh, pbl;
        unsigned v0, v1, v2, v3;
        v0 = __float_as_uint(pFL[0]); v1 = __float_as_uint(pFL[1]);
        v2 = __float_as_uint(pFL[2]); v3 = __float_as_uint(pFL[3]);
        pfh.x = pack_hi(v1, v0); pfh.y = pack_hi(v3, v2);
        pfl.x = cvt_pk_bf16(pFL[0] - __uint_as_float(v0 & 0xffff0000u),
                            pFL[1] - __uint_as_float(v1 & 0xffff0000u));
        pfl.y = cvt_pk_bf16(pFL[2] - __uint_as_float(v2 & 0xffff0000u),
                            pFL[3] - __uint_as_float(v3 & 0xffff0000u));
        v0 = __float_as_uint(pFH[0]); v1 = __float_as_uint(pFH[1]);
        v2 = __float_as_uint(pFH[2]); v3 = __float_as_uint(pFH[3]);
        pfh.z = pack_hi(v1, v0); pfh.w = pack_hi(v3, v2);
        pfl.z = cvt_pk_bf16(pFH[0] - __uint_as_float(v0 & 0xffff0000u),
                            pFH[1] - __uint_as_float(v1 & 0xffff0000u));
        pfl.w = cvt_pk_bf16(pFH[2] - __uint_as_float(v2 & 0xffff0000u),
                            pFH[3] - __uint_as_float(v3 & 0xffff0000u));
        v0 = __float_as_uint(pBL[0]); v1 = __float_as_uint(pBL[1]);
        v2 = __float_as_uint(pBL[2]); v3 = __float_as_uint(pBL[3]);
        pbh.x = pack_hi(v1, v0); pbh.y = pack_hi(v3, v2);
        pbl.x = cvt_pk_bf16(pBL[0] - __uint_as_float(v0 & 0xffff0000u),
                            pBL[1] - __uint_as_float(v1 & 0xffff0000u));
        pbl.y = cvt_pk_bf16(pBL[2] - __uint_as_float(v2 & 0xffff0000u),
                            pBL[3] - __uint_as_float(v3 & 0xffff0000u));
        v0 = __float_as_uint(pBH[0]); v1 = __float_as_uint(pBH[1]);
        v2 = __float_as_uint(pBH[2]); v3 = __float_as_uint(pBH[3]);
        pbh.z = pack_hi(v1, v0); pbh.w = pack_hi(v3, v2);
        pbl.z = cvt_pk_bf16(pBH[0] - __uint_as_float(v0 & 0xffff0000u),
                            pBH[1] - __uint_as_float(v1 & 0xffff0000u));
        pbl.w = cvt_pk_bf16(pBH[2] - __uint_as_float(v2 & 0xffff0000u),
                            pBH[3] - __uint_as_float(v3 & 0xffff0000u));
        const s16x8 BpFh = __builtin_bit_cast(s16x8, pfh);
        const s16x8 BpFl = __builtin_bit_cast(s16x8, pfl);
        const s16x8 BpBh = __builtin_bit_cast(s16x8, pbh);
        const s16x8 BpBl = __builtin_bit_cast(s16x8, pbl);

#pragma unroll
        for (int tt = 0; tt < 8; ++tt) {
            const s16x8 A0 = *(const s16x8*)(ws + OFF_ADEC + tt * 1024u + l * 16u);
            const s16x8 A1 = *(const s16x8*)(ws + OFF_ADEC + 8192u + tt * 1024u + l * 16u);
            const float4 bd = *(const float4*)(b_dec + tt * 16 + 4 * q);
            f32x4 acc = {bd.x, bd.y, bd.z, bd.w};
            acc = MFMA_B16(A0, BpFl, acc);
            acc = MFMA_B16(A1, BpBl, acc);
            acc = MFMA_B16(A0, BpFh, acc);
            acc = MFMA_B16(A1, BpBh, acc);
            *(float4*)(out + (size_t)(rowbase + n) * 128 + tt * 16 + 4 * q) =
                make_float4(acc[0], acc[1], acc[2], acc[3]);
        }
    }
}

extern "C" void kernel_launch(void* const* d_in, const int* in_sizes, int n_in,
                              void* d_out, int out_size, void* d_ws, size_t ws_size,
                              hipStream_t stream)
{
    const float* x    = (const float*)d_in[0];
    const float* w1   = (const float*)d_in[1];
    const float* b1   = (const float*)d_in[2];
    const float* w2   = (const float*)d_in[3];
    const float* b2   = (const float*)d_in[4];
    const float* wihf = (const float*)d_in[5];
    const float* whhf = (const float*)d_in[6];
    const float* bihf = (const float*)d_in[7];
    const float* bhhf = (const float*)d_in[8];
    const float* wihb = (const float*)d_in[9];
    const float* whhb = (const float*)d_in[10];
    const float* bihb = (const float*)d_in[11];
    const float* bhhb = (const float*)d_in[12];
    const float* wdec = (const float*)d_in[13];
    const float* bdec = (const float*)d_in[14];
    float* out = (float*)d_out;
    unsigned char* ws = (unsigned char*)d_ws;

    const int B = in_sizes[0] / SEQB;  // 32768
    const int grid = B / 64;           // 64 rows per 256-thread (4-wave) block

    hipLaunchKernelGGL(gru_precompute_kernel, dim3(1), dim3(1024), 0, stream,
                       wihf, bihf, wihb, bihb, w2, b2, whhf, whhb, bhhf, bhhb, wdec, ws);
    hipLaunchKernelGGL(gru_mfma_kernel, dim3(grid), dim3(256), 0, stream,
                       x, w1, b1, bhhf, bhhb, ws, bdec, out);
}

// Round 18
// 72.603 us; speedup vs baseline: 1.0066x; 1.0066x over previous
//
#include <hip/hip_runtime.h>

// TimeTempTransformerModule: MLP(1->16->32) -> biGRU(H=32, SEQ=32) -> meanpool -> dec(64->128)
// B = 32768 rows, fp32 in/out.
//
// FINAL (v12 restore): best passing configuration, 72.7us, absmax 1.953e-3.
//  - Swapped-operand MFMA recurrence: g^T = W @ h^T; D-layout of step s IS the
//    B-layout of step s+1 under k-perm pi(q,e) baked into precomputed A-frags.
//  - 2-term gh = rne(W) * (h_hi + h_lo): 18 MFMA/step; h split keeps recurrence
//    error at the output-quantization floor (1-term fails at 8.8e-3 > 7.46e-3).
//  - r/z gates: -log2e folded into weights+biases -> sigmoid = rcp(1+exp2(a)).
//  - biases ride in dead k>=16 slots of the gx A-frag (paired with 1.0 in B).
//  - h1 rebuilt in-lane from x registers; ZERO LDS, no barriers in step loop.
//  - 4 independent waves per 256-thread block (16 rows each).
// Exploration record: TLP capped structurally (2048 waves = 2/SIMD; v5=v7=v10
// flat); fused-direction ILP fails on regfile (v8/v9) or accuracy edge (v15);
// further instruction cuts fail accuracy (v13/v15: 8.4-8.8e-3 at the cliff).

#define SEQB 32
#define NH   16
#define DH   32

typedef __attribute__((ext_vector_type(4))) float f32x4;
typedef __attribute__((ext_vector_type(8))) short s16x8;
typedef __attribute__((ext_vector_type(4))) unsigned int u32x4;

#define MFMA_B16(a, b, c) __builtin_amdgcn_mfma_f32_16x16x32_bf16((a), (b), (c), 0, 0, 0)

#define NLOG2E -1.4426950408889634f
#define TWOLOG2E 2.8853900817779268f

// ws layout (bytes)
#define OFF_AHI  0u        // [dir][t<6][lane<64] 16B  gh weights hi (trunc)
#define OFF_ALO  12288u    // [dir][t<6][lane] 16B     gh weights lo (rne resid)  [unused in 2-term-hi/lo-as-one; kept for layout]
#define OFF_AGX  24576u    // [dir][t<6][lane] 16B     gx weights (rne) + bias slots
#define OFF_ADEC 36864u    // [kc<2][t<8][lane] 16B    decoder weights (rne)
#define OFF_WC   53248u    // [dir][96][16] f32 temp
#define OFF_BC   65536u    // [dir][96] f32 temp

__device__ __forceinline__ unsigned short bf16_rne(float x) {
    unsigned u = __float_as_uint(x);
    return (unsigned short)((u + 0x7fffu + ((u >> 16) & 1u)) >> 16);
}
// (a & 0xffff0000) | (b >> 16)  -- packs bf16(b) into lo16, bf16(a) into hi16 (trunc)
__device__ __forceinline__ unsigned pack_hi(unsigned a, unsigned b) {
    return __builtin_amdgcn_perm(a, b, 0x07060302u);
}
__device__ __forceinline__ int kperm(int q, int e) {  // pi(q,e)
    return (e < 4) ? (4 * q + e) : (4 * q + 12 + e);
}

__global__ __launch_bounds__(1024) void gru_precompute_kernel(
    const float* __restrict__ w_ih_f, const float* __restrict__ b_ih_f,
    const float* __restrict__ w_ih_b, const float* __restrict__ b_ih_b,
    const float* __restrict__ w2, const float* __restrict__ b2,
    const float* __restrict__ whh_f, const float* __restrict__ whh_b,
    const float* __restrict__ bhh_f, const float* __restrict__ bhh_b,
    const float* __restrict__ w_dec,
    unsigned char* __restrict__ ws)
{
    const int t = threadIdx.x;
    float* WC = (float*)(ws + OFF_WC);
    float* BC = (float*)(ws + OFF_BC);

    if (t < 192) {  // Wc = w_ih@w2 [96x16], bc = w_ih@b2 + b_ih
        const int dir = t / 96, g = t % 96;
        const float* wih = dir ? w_ih_b : w_ih_f;
        const float* bih = dir ? b_ih_b : b_ih_f;
        float acc[NH];
#pragma unroll
        for (int m = 0; m < NH; ++m) acc[m] = 0.0f;
        float ab = bih[g];
        for (int d = 0; d < DH; ++d) {
            float wv = wih[g * DH + d];
            ab = fmaf(wv, b2[d], ab);
#pragma unroll
            for (int m = 0; m < NH; ++m) acc[m] = fmaf(wv, w2[d * NH + m], acc[m]);
        }
#pragma unroll
        for (int m = 0; m < NH; ++m) WC[(dir * 96 + g) * NH + m] = acc[m];
        BC[dir * 96 + g] = ab;
    }
    __syncthreads();

    if (t < 768) {  // gh A-frags (rne, k-permuted) + gx A-frags (rne + bias slots)
        const int dir = t / 384, r = t % 384, tt = r / 64, l = r % 64;
        const int gate = tt * 16 + (l & 15);
        const int q = l >> 4;
        const float* whh = dir ? whh_b : whh_f;
        const float* bhh = dir ? bhh_b : bhh_f;
        // r/z gates (0..63): fold -log2e so sigma(x) = rcp(1+exp2(a)) directly.
        const float sc = (gate < 64) ? NLOG2E : 1.0f;
        unsigned short h8[8], g8[8];
#pragma unroll
        for (int e = 0; e < 8; ++e) {
            const int u = kperm(q, e);
            h8[e] = bf16_rne(whh[gate * DH + u] * sc);
            float gxv = (e < 4) ? WC[(dir * 96 + gate) * NH + 4 * q + e] : 0.0f;
            g8[e] = bf16_rne(gxv * sc);
        }
        // bias slots: (q=0,e=4) hi, (q=1,e=4) lo; pairs with constant 1.0 in B.
        // r/z: (bc + bhh) * -log2e ; n: bc only (bhh_n applied in g4/g5 C-init).
        const float bias = (BC[dir * 96 + gate] + ((gate < 64) ? bhh[gate] : 0.0f)) * sc;
        const unsigned bb = __float_as_uint(bias);
        if (q == 0) g8[4] = (unsigned short)(bb >> 16);
        if (q == 1) g8[4] = bf16_rne(bias - __uint_as_float(bb & 0xffff0000u));

        unsigned short* dh = (unsigned short*)(ws + OFF_AHI + dir * 6144u + tt * 1024u + l * 16u);
        unsigned short* dg = (unsigned short*)(ws + OFF_AGX + dir * 6144u + tt * 1024u + l * 16u);
#pragma unroll
        for (int e = 0; e < 8; ++e) { dh[e] = h8[e]; dg[e] = g8[e]; }
    }
    {  // decoder A-frags: A[out][k] k-permuted, k = pi(q,e) + 32*kc
        const int kc = t / 512, r = t % 512, tt = r / 64, l = r % 64;
        const int outn = tt * 16 + (l & 15);
        const int q = l >> 4;
        unsigned short* dd = (unsigned short*)(ws + OFF_ADEC + kc * 8192u + tt * 1024u + l * 16u);
#pragma unroll
        for (int e = 0; e < 8; ++e)
            dd[e] = bf16_rne(w_dec[outn * 64 + kperm(q, e) + 32 * kc]);
    }
}

__global__ __launch_bounds__(256, 2) void gru_mfma_kernel(
    const float* __restrict__ x,
    const float* __restrict__ w1, const float* __restrict__ b1,
    const float* __restrict__ bhh_f, const float* __restrict__ bhh_b,
    const unsigned char* __restrict__ ws,
    const float* __restrict__ b_dec,
    float* __restrict__ out)
{
    const int tid = threadIdx.x;
    const int wv  = tid >> 6;   // wave in block (0..3), fully independent
    const int l   = tid & 63;
    const int n = l & 15;       // batch row (D col / B col)
    const int q = l >> 4;       // k-quad / D row-quad
    const int rowbase = blockIdx.x * 64 + wv * 16;
    const float* xr = x + (size_t)(rowbase + n) * SEQB;

    const float4 w1q = *(const float4*)(w1 + 4 * q);  // h1 units 4q..4q+3
    const float4 b1q = *(const float4*)(b1 + 4 * q);

    float pFL[4], pFH[4], pBL[4], pBH[4];

#pragma unroll 1
    for (int dir = 0; dir < 2; ++dir) {
        const float* bhh = dir ? bhh_b : bhh_f;
        const unsigned char* pAhi = ws + OFF_AHI + dir * 6144u + l * 16u;
        const unsigned char* pAgx = ws + OFF_AGX + dir * 6144u + l * 16u;
        s16x8 Ahi[6], Agx[6];
#pragma unroll
        for (int tt = 0; tt < 6; ++tt) {
            Ahi[tt] = *(const s16x8*)(pAhi + tt * 1024);
            Agx[tt] = *(const s16x8*)(pAgx + tt * 1024);
        }
#pragma unroll
        for (int tt = 0; tt < 6; ++tt)
            asm volatile("" : "+v"(Ahi[tt]), "+v"(Agx[tt]));
        // n-gate gh bias (C-init of the gh chain): gates 64+4q+rg (tile4), 80+4q+rg (tile5)
        const float4 bn0f = *(const float4*)(bhh + 64 + 4 * q);
        const float4 bn1f = *(const float4*)(bhh + 80 + 4 * q);
        const f32x4 bhn0 = {bn0f.x, bn0f.y, bn0f.z, bn0f.w};
        const f32x4 bhn1 = {bn1f.x, bn1f.y, bn1f.z, bn1f.w};

        float hL[4] = {0, 0, 0, 0}, hH[4] = {0, 0, 0, 0};
        float pL[4] = {0, 0, 0, 0}, pH[4] = {0, 0, 0, 0};

#pragma unroll 1
        for (int blk = 0; blk < 4; ++blk) {
            const int bb = dir ? 3 - blk : blk;
            const float4 xa = *(const float4*)(xr + bb * 8);
            const float4 xb = *(const float4*)(xr + bb * 8 + 4);
            const float raw[8] = {xa.x, xa.y, xa.z, xa.w, xb.x, xb.y, xb.z, xb.w};
            float xs[8];
#pragma unroll
            for (int i = 0; i < 8; ++i) xs[i] = dir ? raw[7 - i] : raw[i];

#pragma unroll
            for (int i = 0; i < 8; ++i) {
                // ---- B_h1 frag: h1[row n][4q+e] e<4 (in-lane), e4=1.0 (bias), e5..7=0
                float t0 = fmaf(xs[i], w1q.x, b1q.x); t0 = fmaxf(t0, 0.01f * t0);
                float t1 = fmaf(xs[i], w1q.y, b1q.y); t1 = fmaxf(t1, 0.01f * t1);
                float t2 = fmaf(xs[i], w1q.z, b1q.z); t2 = fmaxf(t2, 0.01f * t2);
                float t3 = fmaf(xs[i], w1q.w, b1q.w); t3 = fmaxf(t3, 0.01f * t3);
                u32x4 ub1;
                ub1.x = pack_hi(__float_as_uint(t1), __float_as_uint(t0));
                ub1.y = pack_hi(__float_as_uint(t3), __float_as_uint(t2));
                ub1.z = 0x00003F80u;  // e4 = 1.0 (bias partner), e5 = 0
                ub1.w = 0u;           // e6, e7 = 0
                const s16x8 Bh1 = __builtin_bit_cast(s16x8, ub1);

                // ---- B_h frags hi/lo from in-lane h state (u-order: L=4q+rg, H=16+4q+rg)
                unsigned uL0 = __float_as_uint(hL[0]), uL1 = __float_as_uint(hL[1]);
                unsigned uL2 = __float_as_uint(hL[2]), uL3 = __float_as_uint(hL[3]);
                unsigned uH0 = __float_as_uint(hH[0]), uH1 = __float_as_uint(hH[1]);
                unsigned uH2 = __float_as_uint(hH[2]), uH3 = __float_as_uint(hH[3]);
                u32x4 phh;
                phh.x = pack_hi(uL1, uL0); phh.y = pack_hi(uL3, uL2);
                phh.z = pack_hi(uH1, uH0); phh.w = pack_hi(uH3, uH2);
                float lL0 = hL[0] - __uint_as_float(uL0 & 0xffff0000u);
                float lL1 = hL[1] - __uint_as_float(uL1 & 0xffff0000u);
                float lL2 = hL[2] - __uint_as_float(uL2 & 0xffff0000u);
                float lL3 = hL[3] - __uint_as_float(uL3 & 0xffff0000u);
                float lH0 = hH[0] - __uint_as_float(uH0 & 0xffff0000u);
                float lH1 = hH[1] - __uint_as_float(uH1 & 0xffff0000u);
                float lH2 = hH[2] - __uint_as_float(uH2 & 0xffff0000u);
                float lH3 = hH[3] - __uint_as_float(uH3 & 0xffff0000u);
                u32x4 phl;
                phl.x = pack_hi(__float_as_uint(lL1), __float_as_uint(lL0));
                phl.y = pack_hi(__float_as_uint(lL3), __float_as_uint(lL2));
                phl.z = pack_hi(__float_as_uint(lH1), __float_as_uint(lH0));
                phl.w = pack_hi(__float_as_uint(lH3), __float_as_uint(lH2));
                const s16x8 Bhhi = __builtin_bit_cast(s16x8, phh);
                const s16x8 Bhlo = __builtin_bit_cast(s16x8, phl);

                const f32x4 z4 = {0.0f, 0.0f, 0.0f, 0.0f};
                // r tiles: gx+bias then 2-term gh (rne W x (h_lo, h_hi)), one chain
                f32x4 a0 = MFMA_B16(Agx[0], Bh1, z4);
                a0 = MFMA_B16(Ahi[0], Bhlo, a0); a0 = MFMA_B16(Ahi[0], Bhhi, a0);
                f32x4 a1 = MFMA_B16(Agx[1], Bh1, z4);
                a1 = MFMA_B16(Ahi[1], Bhlo, a1); a1 = MFMA_B16(Ahi[1], Bhhi, a1);
                // z tiles
                f32x4 a2 = MFMA_B16(Agx[2], Bh1, z4);
                a2 = MFMA_B16(Ahi[2], Bhlo, a2); a2 = MFMA_B16(Ahi[2], Bhhi, a2);
                f32x4 a3 = MFMA_B16(Agx[3], Bh1, z4);
                a3 = MFMA_B16(Ahi[3], Bhlo, a3); a3 = MFMA_B16(Ahi[3], Bhhi, a3);
                // n tiles: gx (with bcn in bias slot) and gh (C-init = bhn) kept separate
                f32x4 x4a = MFMA_B16(Agx[4], Bh1, z4);
                f32x4 x5a = MFMA_B16(Agx[5], Bh1, z4);
                f32x4 g4 = MFMA_B16(Ahi[4], Bhlo, bhn0);
                g4 = MFMA_B16(Ahi[4], Bhhi, g4);
                f32x4 g5 = MFMA_B16(Ahi[5], Bhlo, bhn1);
                g5 = MFMA_B16(Ahi[5], Bhhi, g5);

                // ---- activations + state update (fp32; r/z pre-scaled by -log2e)
#pragma unroll
                for (int rg = 0; rg < 4; ++rg) {
                    float rL = __builtin_amdgcn_rcpf(1.0f + __builtin_amdgcn_exp2f(a0[rg]));
                    float zL = __builtin_amdgcn_rcpf(1.0f + __builtin_amdgcn_exp2f(a2[rg]));
                    float tL = fmaf(rL, g4[rg], x4a[rg]);
                    float nL = fmaf(-2.0f, __builtin_amdgcn_rcpf(1.0f + __builtin_amdgcn_exp2f(tL * TWOLOG2E)), 1.0f);
                    hL[rg] = fmaf(zL, hL[rg] - nL, nL);
                    pL[rg] += hL[rg];

                    float rH = __builtin_amdgcn_rcpf(1.0f + __builtin_amdgcn_exp2f(a1[rg]));
                    float zH = __builtin_amdgcn_rcpf(1.0f + __builtin_amdgcn_exp2f(a3[rg]));
                    float tH = fmaf(rH, g5[rg], x5a[rg]);
                    float nH = fmaf(-2.0f, __builtin_amdgcn_rcpf(1.0f + __builtin_amdgcn_exp2f(tH * TWOLOG2E)), 1.0f);
                    hH[rg] = fmaf(zH, hH[rg] - nH, nH);
                    pH[rg] += hH[rg];
                }
            }
        }
        if (dir == 0) {
#pragma unroll
            for (int rg = 0; rg < 4; ++rg) { pFL[rg] = pL[rg]; pFH[rg] = pH[rg]; }
        } else {
#pragma unroll
            for (int rg = 0; rg < 4; ++rg) { pBL[rg] = pL[rg]; pBH[rg] = pH[rg]; }
        }
    }

    // ---- decoder: out[16x128] = pooled[16x64] @ w_dec^T + b_dec (swapped MFMA)
    {
#pragma unroll
        for (int rg = 0; rg < 4; ++rg) {
            pFL[rg] *= 0.03125f; pFH[rg] *= 0.03125f;
            pBL[rg] *= 0.03125f; pBH[rg] *= 0.03125f;
        }
        u32x4 pfh, pfl, pbh, pbl;
        unsigned v0, v1, v2, v3;
        v0 = __float_as_uint(pFL[0]); v1 = __float_as_uint(pFL[1]);
        v2 = __float_as_uint(pFL[2]); v3 = __float_as_uint(pFL[3]);
        pfh.x = pack_hi(v1, v0); pfh.y = pack_hi(v3, v2);
        pfl.x = pack_hi(__float_as_uint(pFL[1] - __uint_as_float(v1 & 0xffff0000u)),
                        __float_as_uint(pFL[0] - __uint_as_float(v0 & 0xffff0000u)));
        pfl.y = pack_hi(__float_as_uint(pFL[3] - __uint_as_float(v3 & 0xffff0000u)),
                        __float_as_uint(pFL[2] - __uint_as_float(v2 & 0xffff0000u)));
        v0 = __float_as_uint(pFH[0]); v1 = __float_as_uint(pFH[1]);
        v2 = __float_as_uint(pFH[2]); v3 = __float_as_uint(pFH[3]);
        pfh.z = pack_hi(v1, v0); pfh.w = pack_hi(v3, v2);
        pfl.z = pack_hi(__float_as_uint(pFH[1] - __uint_as_float(v1 & 0xffff0000u)),
                        __float_as_uint(pFH[0] - __uint_as_float(v0 & 0xffff0000u)));
        pfl.w = pack_hi(__float_as_uint(pFH[3] - __uint_as_float(v3 & 0xffff0000u)),
                        __float_as_uint(pFH[2] - __uint_as_float(v2 & 0xffff0000u)));
        v0 = __float_as_uint(pBL[0]); v1 = __float_as_uint(pBL[1]);
        v2 = __float_as_uint(pBL[2]); v3 = __float_as_uint(pBL[3]);
        pbh.x = pack_hi(v1, v0); pbh.y = pack_hi(v3, v2);
        pbl.x = pack_hi(__float_as_uint(pBL[1] - __uint_as_float(v1 & 0xffff0000u)),
                        __float_as_uint(pBL[0] - __uint_as_float(v0 & 0xffff0000u)));
        pbl.y = pack_hi(__float_as_uint(pBL[3] - __uint_as_float(v3 & 0xffff0000u)),
                        __float_as_uint(pBL[2] - __uint_as_float(v2 & 0xffff0000u)));
        v0 = __float_as_uint(pBH[0]); v1 = __float_as_uint(pBH[1]);
        v2 = __float_as_uint(pBH[2]); v3 = __float_as_uint(pBH[3]);
        pbh.z = pack_hi(v1, v0); pbh.w = pack_hi(v3, v2);
        pbl.z = pack_hi(__float_as_uint(pBH[1] - __uint_as_float(v1 & 0xffff0000u)),
                        __float_as_uint(pBH[0] - __uint_as_float(v0 & 0xffff0000u)));
        pbl.w = pack_hi(__float_as_uint(pBH[3] - __uint_as_float(v3 & 0xffff0000u)),
                        __float_as_uint(pBH[2] - __uint_as_float(v2 & 0xffff0000u)));
        const s16x8 BpFh = __builtin_bit_cast(s16x8, pfh);
        const s16x8 BpFl = __builtin_bit_cast(s16x8, pfl);
        const s16x8 BpBh = __builtin_bit_cast(s16x8, pbh);
        const s16x8 BpBl = __builtin_bit_cast(s16x8, pbl);

#pragma unroll
        for (int tt = 0; tt < 8; ++tt) {
            const s16x8 A0 = *(const s16x8*)(ws + OFF_ADEC + tt * 1024u + l * 16u);
            const s16x8 A1 = *(const s16x8*)(ws + OFF_ADEC + 8192u + tt * 1024u + l * 16u);
            const float4 bd = *(const float4*)(b_dec + tt * 16 + 4 * q);
            f32x4 acc = {bd.x, bd.y, bd.z, bd.w};
            acc = MFMA_B16(A0, BpFl, acc);
            acc = MFMA_B16(A1, BpBl, acc);
            acc = MFMA_B16(A0, BpFh, acc);
            acc = MFMA_B16(A1, BpBh, acc);
            *(float4*)(out + (size_t)(rowbase + n) * 128 + tt * 16 + 4 * q) =
                make_float4(acc[0], acc[1], acc[2], acc[3]);
        }
    }
}

extern "C" void kernel_launch(void* const* d_in, const int* in_sizes, int n_in,
                              void* d_out, int out_size, void* d_ws, size_t ws_size,
                              hipStream_t stream)
{
    const float* x    = (const float*)d_in[0];
    const float* w1   = (const float*)d_in[1];
    const float* b1   = (const float*)d_in[2];
    const float* w2   = (const float*)d_in[3];
    const float* b2   = (const float*)d_in[4];
    const float* wihf = (const float*)d_in[5];
    const float* whhf = (const float*)d_in[6];
    const float* bihf = (const float*)d_in[7];
    const float* bhhf = (const float*)d_in[8];
    const float* wihb = (const float*)d_in[9];
    const float* whhb = (const float*)d_in[10];
    const float* bihb = (const float*)d_in[11];
    const float* bhhb = (const float*)d_in[12];
    const float* wdec = (const float*)d_in[13];
    const float* bdec = (const float*)d_in[14];
    float* out = (float*)d_out;
    unsigned char* ws = (unsigned char*)d_ws;

    const int B = in_sizes[0] / SEQB;  // 32768
    const int grid = B / 64;           // 64 rows per 256-thread (4-wave) block

    hipLaunchKernelGGL(gru_precompute_kernel, dim3(1), dim3(1024), 0, stream,
                       wihf, bihf, wihb, bihb, w2, b2, whhf, whhb, bhhf, bhhb, wdec, ws);
    hipLaunchKernelGGL(gru_mfma_kernel, dim3(grid), dim3(256), 0, stream,
                       x, w1, b1, bhhf, bhhb, ws, bdec, out);
}